// Round 7
// baseline (519.993 us; speedup 1.0000x reference)
//
#include <hip/hip_runtime.h>
#include <hip/hip_bf16.h>

#define N_   4
#define CIN  1024
#define H_   56
#define W_   56
#define HW   3136
#define CB   256
#define KK   9
#define OFFC 18
#define PTOT (N_ * HW)   // 12544

typedef __attribute__((ext_vector_type(8))) short short8;
typedef __attribute__((ext_vector_type(4))) short short4v;
typedef __attribute__((ext_vector_type(4))) float float4v;
typedef __attribute__((ext_vector_type(4))) unsigned int uint4v;
typedef unsigned short ushort_t;

// fp32 -> bf16 round-to-nearest-even
__device__ inline ushort_t bf16_rne(float f) {
    unsigned int u = __float_as_uint(f);
    unsigned int r = (u + 0x7FFFu + ((u >> 16) & 1u)) >> 16;
    return (ushort_t)r;
}

// ---------------------------------------------------------------------------
// Pack weights, single-plane bf16.
// w1 [256][1024]     -> w1p [o][1024]
// w2 [256][256][9]   -> w2b [o][K=2304], K = tap*256 + c
// w3 [1024][256]     -> w3p [o][256]
// w_off [18][256][9] -> wofp [tap][32][256]  (m padded 18->32 with zeros)
// ---------------------------------------------------------------------------
__global__ void __launch_bounds__(256) pack_weights_kernel(
    const float* __restrict__ w1, const float* __restrict__ w2,
    const float* __restrict__ w3, const float* __restrict__ w_off,
    ushort_t* __restrict__ w1p, ushort_t* __restrict__ w2b,
    ushort_t* __restrict__ w3p, ushort_t* __restrict__ wofp)
{
    int e = blockIdx.x * 256 + threadIdx.x;
    if (e < 256 * 1024) { w1p[e] = bf16_rne(w1[e]); return; }
    e -= 256 * 1024;
    if (e < 256 * 2304) {
        int o = e / 2304, K = e % 2304;
        int kk = K >> 8, c = K & 255;
        w2b[e] = bf16_rne(w2[(o * 256 + c) * 9 + kk]);
        return;
    }
    e -= 256 * 2304;
    if (e < 1024 * 256) { w3p[e] = bf16_rne(w3[e]); return; }
    e -= 1024 * 256;
    if (e < 9 * 32 * 256) {
        int kk = e / (32 * 256);
        int rem = e % (32 * 256);
        int m = rem >> 8, c = rem & 255;
        wofp[e] = (m < OFFC) ? bf16_rne(w_off[((size_t)m * 256 + c) * 9 + kk])
                             : (ushort_t)0;
    }
}

// ---------------------------------------------------------------------------
// Transpose x: NCHW fp32 -> NHWC bf16 xt[p][1024]. 64p x 64c tile via LDS.
// Grid (PTOT/64, CIN/64), 256 thr.
// ---------------------------------------------------------------------------
__global__ void __launch_bounds__(256) transpose_x_kernel(
    const float* __restrict__ x, ushort_t* __restrict__ xt)
{
    __shared__ float T[64][68];
    const int tid   = threadIdx.x;
    const int pBase = blockIdx.x * 64;
    const int cBase = blockIdx.y * 64;
    const int n     = pBase / HW;
    const int pin   = pBase - n * HW;
    const float* xn = x + ((size_t)n * CIN + cBase) * HW + pin;

#pragma unroll
    for (int it = 0; it < 4; ++it) {
        int c  = it * 16 + (tid >> 4);
        int p4 = (tid & 15) * 4;
        float4 v = *reinterpret_cast<const float4*>(&xn[(size_t)c * HW + p4]);
        *reinterpret_cast<float4*>(&T[c][p4]) = v;
    }
    __syncthreads();

    const int p  = tid >> 2;
    const int cs = (tid & 3) * 16;
    unsigned int res[8];
#pragma unroll
    for (int j = 0; j < 8; ++j) {
        ushort_t a = bf16_rne(T[cs + 2 * j][p]);
        ushort_t b = bf16_rne(T[cs + 2 * j + 1][p]);
        res[j] = (unsigned int)a | ((unsigned int)b << 16);
    }
    unsigned int* dst = reinterpret_cast<unsigned int*>(
        &xt[(size_t)(pBase + p) * 1024 + cBase + cs]);
    *reinterpret_cast<uint4v*>(dst)     = uint4v{res[0], res[1], res[2], res[3]};
    *reinterpret_cast<uint4v*>(dst + 4) = uint4v{res[4], res[5], res[6], res[7]};
}

// ---------------------------------------------------------------------------
// conv1: rt[p][o] = relu(b1[o] + sum_c xt[p][c] w1[o][c]). Barrier-free,
// global-fed. Block 256 = 4 waves (2 p-subtiles x 2 o-subtiles); wave tile
// 16p x 64o; K=1024. Grid (PTOT/32, 2) = 784 blocks, 3136 waves.
// ---------------------------------------------------------------------------
__global__ void __launch_bounds__(256, 4) conv1_kernel(
    const ushort_t* __restrict__ xt, const ushort_t* __restrict__ w1p,
    const float* __restrict__ b1, ushort_t* __restrict__ rt)
{
    const int tid  = threadIdx.x;
    const int wave = tid >> 6;
    const int lane = tid & 63;
    const int l15  = lane & 15;
    const int quad = lane >> 4;
    const int pg    = blockIdx.x * 32 + (wave & 1) * 16;
    const int oBase = blockIdx.y * 128 + (wave >> 1) * 64;

    float4v acc[4];
#pragma unroll
    for (int j = 0; j < 4; ++j) acc[j] = (float4v)(0.f);

    const ushort_t* arow = xt + (size_t)(pg + l15) * 1024 + quad * 8;

#pragma unroll 4
    for (int c0 = 0; c0 < 1024; c0 += 32) {
        short8 af = *(const short8*)(arow + c0);
#pragma unroll
        for (int nt = 0; nt < 4; ++nt) {
            short8 bf = *(const short8*)&w1p[(size_t)(oBase + nt * 16 + l15) * 1024 +
                                             c0 + quad * 8];
            acc[nt] = __builtin_amdgcn_mfma_f32_16x16x32_bf16(af, bf, acc[nt], 0, 0, 0);
        }
    }

#pragma unroll
    for (int rr = 0; rr < 4; ++rr) {
        int p_row = pg + quad * 4 + rr;
#pragma unroll
        for (int nt = 0; nt < 4; ++nt) {
            int o = oBase + nt * 16 + l15;
            float v = fmaxf(acc[nt][rr] + b1[o], 0.f);
            rt[(size_t)p_row * 256 + o] = bf16_rne(v);
        }
    }
}

// ---------------------------------------------------------------------------
// offset conv, tap-split K-parallel: each block handles ONE tap; partial
// results accumulated with fp32 atomicAdd into zero-initialized offb.
// Block 256 = 4 waves (4 p-subtiles); wave tile 16p x 32m, K=256.
// Grid (PTOT/64, 9) = 1764 blocks, 7056 waves.
// ---------------------------------------------------------------------------
__global__ void __launch_bounds__(256, 4) offset_kernel(
    const ushort_t* __restrict__ rt, const ushort_t* __restrict__ wofp,
    float* __restrict__ offb)
{
    const int tid  = threadIdx.x;
    const int wave = tid >> 6;
    const int lane = tid & 63;
    const int l15  = lane & 15;
    const int quad = lane >> 4;
    const int tap  = blockIdx.y;
    const int ky   = tap / 3 - 1, kx = tap % 3 - 1;
    const int pg   = blockIdx.x * 64 + wave * 16;
    const int n    = pg / HW;
    const int pi   = pg - n * HW;

    const int pl = pi + l15;
    const int h  = pl / W_, w = pl - h * W_;
    const int hy = h + ky, xr = w + kx;
    const bool valid = (hy >= 0) && (hy < H_) && (xr >= 0) && (xr < W_);
    const int hyc = min(max(hy, 0), H_ - 1);
    const int xc  = min(max(xr, 0), W_ - 1);
    const ushort_t* arow = rt + ((size_t)n * HW + hyc * W_ + xc) * 256 + quad * 8;

    float4v acc[2];
    acc[0] = (float4v)(0.f);
    acc[1] = (float4v)(0.f);

#pragma unroll
    for (int c0 = 0; c0 < 256; c0 += 32) {
        short8 af = valid ? *(const short8*)(arow + c0) : (short8)0;
#pragma unroll
        for (int nt = 0; nt < 2; ++nt) {
            short8 bf = *(const short8*)&wofp[(size_t)(tap * 32 + nt * 16 + l15) * 256 +
                                              c0 + quad * 8];
            acc[nt] = __builtin_amdgcn_mfma_f32_16x16x32_bf16(af, bf, acc[nt], 0, 0, 0);
        }
    }

#pragma unroll
    for (int nt = 0; nt < 2; ++nt) {
        int m = nt * 16 + l15;
        if (m < OFFC) {
#pragma unroll
            for (int rr = 0; rr < 4; ++rr) {
                int pi_row = pi + quad * 4 + rr;
                atomicAdd(&offb[((size_t)n * OFFC + m) * HW + pi_row], acc[nt][rr]);
            }
        }
    }
}

// ---------------------------------------------------------------------------
// deform conv: barrier-free global-fed. Wave tile 16p x 64o; block 256 = 4
// waves (2p x 2o). Grid (PTOT/32, 2) = 784 blocks, 3136 waves (3+/SIMD).
// A-fragments built in registers from 4 bilinear-corner 16B loads of NHWC rt.
// b_off folded into offset read (offb holds bias-free conv partials).
// ---------------------------------------------------------------------------
__global__ void __launch_bounds__(256, 4) deform_kernel(
    const ushort_t* __restrict__ rt, const float* __restrict__ offb,
    const float* __restrict__ b_off, const ushort_t* __restrict__ w2b,
    const float* __restrict__ b2, ushort_t* __restrict__ r2t)
{
    const int tid  = threadIdx.x;
    const int wave = tid >> 6;
    const int lane = tid & 63;
    const int l15  = lane & 15;
    const int quad = lane >> 4;
    const int pg    = blockIdx.x * 32 + (wave & 1) * 16;
    const int oBase = blockIdx.y * 128 + (wave >> 1) * 64;
    const int n     = pg / HW;
    const int pi    = pg - n * HW + l15;
    const int h = pi / W_, w = pi - h * W_;
    const ushort_t* rtn = rt + (size_t)n * HW * 256;
    const float* offn   = offb + (size_t)n * OFFC * HW;

    float4v acc[4];
#pragma unroll
    for (int j = 0; j < 4; ++j) acc[j] = (float4v)(0.f);

    for (int kk = 0; kk < KK; ++kk) {
        float dy = offn[(size_t)(2 * kk) * HW + pi] + b_off[2 * kk];
        float dx = offn[(size_t)(2 * kk + 1) * HW + pi] + b_off[2 * kk + 1];
        float ys = (float)(h + kk / 3 - 1) + dy;
        float xs = (float)(w + kk % 3 - 1) + dx;
        float y0f = floorf(ys), x0f = floorf(xs);
        int y0 = (int)y0f, x0 = (int)x0f;
        float wy1 = ys - y0f, wy0 = 1.f - wy1;
        float wx1 = xs - x0f, wx0 = 1.f - wx1;

        float wc[4];
        const ushort_t* cb[4];
#pragma unroll
        for (int u = 0; u < 2; ++u)
#pragma unroll
            for (int v = 0; v < 2; ++v) {
                int yy = y0 + u, xx = x0 + v;
                bool vld = (yy >= 0) && (yy < H_) && (xx >= 0) && (xx < W_);
                wc[u * 2 + v] = vld ? (u ? wy1 : wy0) * (v ? wx1 : wx0) : 0.f;
                int yc = min(max(yy, 0), H_ - 1);
                int xc = min(max(xx, 0), W_ - 1);
                cb[u * 2 + v] = rtn + (size_t)(yc * W_ + xc) * 256 + quad * 8;
            }

#pragma unroll 2
        for (int c0 = 0; c0 < 256; c0 += 32) {
            uint4v cw[4];
#pragma unroll
            for (int j4 = 0; j4 < 4; ++j4)
                cw[j4] = *(const uint4v*)(cb[j4] + c0);
            uint4v afu;
#pragma unroll
            for (int i = 0; i < 4; ++i) {
                float s0 = 0.f, s1 = 0.f;
#pragma unroll
                for (int j4 = 0; j4 < 4; ++j4) {
                    unsigned int u = cw[j4][i];
                    s0 = fmaf(wc[j4], __uint_as_float(u << 16), s0);
                    s1 = fmaf(wc[j4], __uint_as_float(u & 0xffff0000u), s1);
                }
                afu[i] = ((__float_as_uint(s0) + 0x8000u) >> 16) |
                         ((__float_as_uint(s1) + 0x8000u) & 0xffff0000u);
            }
            union { uint4v u; short8 s; } cvt;
            cvt.u = afu;
            short8 af = cvt.s;
#pragma unroll
            for (int nt = 0; nt < 4; ++nt) {
                short8 bf = *(const short8*)&w2b[(size_t)(oBase + nt * 16 + l15) * 2304 +
                                                 kk * 256 + c0 + quad * 8];
                acc[nt] = __builtin_amdgcn_mfma_f32_16x16x32_bf16(af, bf, acc[nt], 0, 0, 0);
            }
        }
    }

#pragma unroll
    for (int rr = 0; rr < 4; ++rr) {
        int p_row = pg + quad * 4 + rr;   // global over PTOT
#pragma unroll
        for (int nt = 0; nt < 4; ++nt) {
            int o = oBase + nt * 16 + l15;
            float v = fmaxf(acc[nt][rr] + b2[o], 0.f);
            r2t[(size_t)p_row * 256 + o] = bf16_rne(v);
        }
    }
}

// ---------------------------------------------------------------------------
// conv3: out = relu(x + w3 . r2 + b3), NCHW fp32 out. Barrier-free.
// Block 256 = 4 waves; M-tile 256 (wave 64 m), N = 64 p. Grid (196, 4).
// ---------------------------------------------------------------------------
__global__ void __launch_bounds__(256, 4) conv3_kernel(
    const ushort_t* __restrict__ w3p, const ushort_t* __restrict__ r2t,
    const float* __restrict__ b3, const float* __restrict__ x,
    float* __restrict__ out)
{
    const int tid  = threadIdx.x;
    const int wave = tid >> 6;
    const int lane = tid & 63;
    const int l15  = lane & 15;
    const int quad = lane >> 4;
    const int pBase = blockIdx.x * 64;
    const int n     = pBase / HW;
    const int p_in  = pBase % HW;
    const int mBase = blockIdx.y * 256 + wave * 64;

    float4v acc[4][4];
#pragma unroll
    for (int i = 0; i < 4; ++i)
#pragma unroll
        for (int j = 0; j < 4; ++j) acc[i][j] = (float4v)(0.f);

#pragma unroll
    for (int c0 = 0; c0 < 256; c0 += 32) {
        short8 bf[4];
#pragma unroll
        for (int nt = 0; nt < 4; ++nt)
            bf[nt] = *(const short8*)&r2t[(size_t)(pBase + nt * 16 + l15) * 256 +
                                          c0 + quad * 8];
#pragma unroll
        for (int mt = 0; mt < 4; ++mt) {
            short8 af = *(const short8*)&w3p[(size_t)(mBase + mt * 16 + l15) * 256 +
                                             c0 + quad * 8];
#pragma unroll
            for (int nt = 0; nt < 4; ++nt)
                acc[mt][nt] = __builtin_amdgcn_mfma_f32_16x16x32_bf16(
                    af, bf[nt], acc[mt][nt], 0, 0, 0);
        }
    }

#pragma unroll
    for (int mt = 0; mt < 4; ++mt)
#pragma unroll
        for (int rr = 0; rr < 4; ++rr) {
            int row = mBase + mt * 16 + quad * 4 + rr;
            float bv = b3[row];
#pragma unroll
            for (int nt = 0; nt < 4; ++nt) {
                int col = p_in + nt * 16 + l15;
                size_t idx = ((size_t)n * CIN + row) * HW + col;
                out[idx] = fmaxf(acc[mt][nt][rr] + bv + x[idx], 0.f);
            }
        }
}

// ---------------------------------------------------------------------------
// kernel_launch
// ---------------------------------------------------------------------------
extern "C" void kernel_launch(void* const* d_in, const int* in_sizes, int n_in,
                              void* d_out, int out_size, void* d_ws, size_t ws_size,
                              hipStream_t stream)
{
    const float* x     = (const float*)d_in[0];
    const float* w1    = (const float*)d_in[1];
    const float* b1    = (const float*)d_in[2];
    const float* w_off = (const float*)d_in[3];
    const float* b_off = (const float*)d_in[4];
    const float* w2    = (const float*)d_in[5];
    const float* b2    = (const float*)d_in[6];
    const float* w3    = (const float*)d_in[7];
    const float* b3    = (const float*)d_in[8];
    float* out = (float*)d_out;

    ushort_t* xt   = (ushort_t*)d_ws;                     // 12,845,056 ush
    ushort_t* rt   = xt + (size_t)PTOT * 1024;            //  3,211,264 ush
    ushort_t* r2t  = rt + (size_t)PTOT * 256;             //  3,211,264 ush
    float*    offb = (float*)(r2t + (size_t)PTOT * 256);  //    225,792 f
    ushort_t* w1p  = (ushort_t*)(offb + (size_t)N_ * OFFC * HW);
    ushort_t* w2b  = w1p + (size_t)256 * 1024;
    ushort_t* w3p  = w2b + (size_t)256 * 2304;
    ushort_t* wofp = w3p + (size_t)1024 * 256;
    // total ~ 42 MB

    // 1) pack weights (all single-plane bf16)
    {
        int total = 256 * 1024 + 256 * 2304 + 1024 * 256 + 9 * 32 * 256;
        pack_weights_kernel<<<(total + 255) / 256, 256, 0, stream>>>(
            w1, w2, w3, w_off, w1p, w2b, w3p, wofp);
    }
    // 2) xt = transpose(x) NHWC bf16
    {
        dim3 grid(PTOT / 64, CIN / 64);
        transpose_x_kernel<<<grid, 256, 0, stream>>>(x, xt);
    }
    // 3) rt = relu(xt . w1^T + b1)
    {
        dim3 grid(PTOT / 32, 2);
        conv1_kernel<<<grid, 256, 0, stream>>>(xt, w1p, b1, rt);
    }
    // 4) offb = conv3x3(rt, w_off)  (bias-free; tap-split atomic accumulate)
    hipMemsetAsync(offb, 0, (size_t)N_ * OFFC * HW * sizeof(float), stream);
    {
        dim3 grid(PTOT / 64, 9);
        offset_kernel<<<grid, 256, 0, stream>>>(rt, wofp, offb);
    }
    // 5) r2t = relu(deform(rt, offb + b_off) . w2 + b2)
    {
        dim3 grid(PTOT / 32, 2);
        deform_kernel<<<grid, 256, 0, stream>>>(rt, offb, b_off, w2b, b2, r2t);
    }
    // 6) out = relu(x + w3 . r2 + b3)
    {
        dim3 grid(PTOT / 64, 4);
        conv3_kernel<<<grid, 256, 0, stream>>>(w3p, r2t, b3, x, out);
    }
}

// Round 8
// 465.722 us; speedup vs baseline: 1.1165x; 1.1165x over previous
//
#include <hip/hip_runtime.h>
#include <hip/hip_bf16.h>

#define N_   4
#define CIN  1024
#define H_   56
#define W_   56
#define HW   3136
#define CB   256
#define KK   9
#define OFFC 18
#define PTOT (N_ * HW)   // 12544

typedef __attribute__((ext_vector_type(8))) short short8;
typedef __attribute__((ext_vector_type(4))) short short4v;
typedef __attribute__((ext_vector_type(4))) float float4v;
typedef __attribute__((ext_vector_type(4))) unsigned int uint4v;
typedef unsigned short ushort_t;

// fp32 -> bf16 round-to-nearest-even
__device__ inline ushort_t bf16_rne(float f) {
    unsigned int u = __float_as_uint(f);
    unsigned int r = (u + 0x7FFFu + ((u >> 16) & 1u)) >> 16;
    return (ushort_t)r;
}

// ---------------------------------------------------------------------------
// Pack weights, single-plane bf16.
// w1 [256][1024]     -> w1p [o][1024]
// w2 [256][256][9]   -> w2b [o][K=2304], K = tap*256 + c
// w3 [1024][256]     -> w3p [o][256]
// w_off [18][256][9] -> wofp [tap][32][256]  (m padded 18->32 with zeros)
// ---------------------------------------------------------------------------
__global__ void __launch_bounds__(256) pack_weights_kernel(
    const float* __restrict__ w1, const float* __restrict__ w2,
    const float* __restrict__ w3, const float* __restrict__ w_off,
    ushort_t* __restrict__ w1p, ushort_t* __restrict__ w2b,
    ushort_t* __restrict__ w3p, ushort_t* __restrict__ wofp)
{
    int e = blockIdx.x * 256 + threadIdx.x;
    if (e < 256 * 1024) { w1p[e] = bf16_rne(w1[e]); return; }
    e -= 256 * 1024;
    if (e < 256 * 2304) {
        int o = e / 2304, K = e % 2304;
        int kk = K >> 8, c = K & 255;
        w2b[e] = bf16_rne(w2[(o * 256 + c) * 9 + kk]);
        return;
    }
    e -= 256 * 2304;
    if (e < 1024 * 256) { w3p[e] = bf16_rne(w3[e]); return; }
    e -= 1024 * 256;
    if (e < 9 * 32 * 256) {
        int kk = e / (32 * 256);
        int rem = e % (32 * 256);
        int m = rem >> 8, c = rem & 255;
        wofp[e] = (m < OFFC) ? bf16_rne(w_off[((size_t)m * 256 + c) * 9 + kk])
                             : (ushort_t)0;
    }
}

// ---------------------------------------------------------------------------
// Transpose x: NCHW fp32 -> NHWC bf16 xt[p][1024]. 64p x 64c tile via LDS.
// ---------------------------------------------------------------------------
__global__ void __launch_bounds__(256) transpose_x_kernel(
    const float* __restrict__ x, ushort_t* __restrict__ xt)
{
    __shared__ float T[64][68];
    const int tid   = threadIdx.x;
    const int pBase = blockIdx.x * 64;
    const int cBase = blockIdx.y * 64;
    const int n     = pBase / HW;
    const int pin   = pBase - n * HW;
    const float* xn = x + ((size_t)n * CIN + cBase) * HW + pin;

#pragma unroll
    for (int it = 0; it < 4; ++it) {
        int c  = it * 16 + (tid >> 4);
        int p4 = (tid & 15) * 4;
        float4 v = *reinterpret_cast<const float4*>(&xn[(size_t)c * HW + p4]);
        *reinterpret_cast<float4*>(&T[c][p4]) = v;
    }
    __syncthreads();

    const int p  = tid >> 2;
    const int cs = (tid & 3) * 16;
    unsigned int res[8];
#pragma unroll
    for (int j = 0; j < 8; ++j) {
        ushort_t a = bf16_rne(T[cs + 2 * j][p]);
        ushort_t b = bf16_rne(T[cs + 2 * j + 1][p]);
        res[j] = (unsigned int)a | ((unsigned int)b << 16);
    }
    unsigned int* dst = reinterpret_cast<unsigned int*>(
        &xt[(size_t)(pBase + p) * 1024 + cBase + cs]);
    *reinterpret_cast<uint4v*>(dst)     = uint4v{res[0], res[1], res[2], res[3]};
    *reinterpret_cast<uint4v*>(dst + 4) = uint4v{res[4], res[5], res[6], res[7]};
}

// ---------------------------------------------------------------------------
// conv1: rt[p][o] = relu(b1[o] + sum_c xt[p][c] w1[o][c]). Barrier-free,
// global-fed, K-loop fully unrolled. Wave 16p x 64o. Grid (PTOT/32, 2).
// ---------------------------------------------------------------------------
__global__ void __launch_bounds__(256, 4) conv1_kernel(
    const ushort_t* __restrict__ xt, const ushort_t* __restrict__ w1p,
    const float* __restrict__ b1, ushort_t* __restrict__ rt)
{
    const int tid  = threadIdx.x;
    const int wave = tid >> 6;
    const int lane = tid & 63;
    const int l15  = lane & 15;
    const int quad = lane >> 4;
    const int pg    = blockIdx.x * 32 + (wave & 1) * 16;
    const int oBase = blockIdx.y * 128 + (wave >> 1) * 64;

    float4v acc[4];
#pragma unroll
    for (int j = 0; j < 4; ++j) acc[j] = (float4v)(0.f);

    const ushort_t* arow = xt + (size_t)(pg + l15) * 1024 + quad * 8;

#pragma unroll
    for (int c0 = 0; c0 < 1024; c0 += 32) {
        short8 af = *(const short8*)(arow + c0);
#pragma unroll
        for (int nt = 0; nt < 4; ++nt) {
            short8 bf = *(const short8*)&w1p[(size_t)(oBase + nt * 16 + l15) * 1024 +
                                             c0 + quad * 8];
            acc[nt] = __builtin_amdgcn_mfma_f32_16x16x32_bf16(af, bf, acc[nt], 0, 0, 0);
        }
    }

#pragma unroll
    for (int rr = 0; rr < 4; ++rr) {
        int p_row = pg + quad * 4 + rr;
#pragma unroll
        for (int nt = 0; nt < 4; ++nt) {
            int o = oBase + nt * 16 + l15;
            float v = fmaxf(acc[nt][rr] + b1[o], 0.f);
            rt[(size_t)p_row * 256 + o] = bf16_rne(v);
        }
    }
}

// ---------------------------------------------------------------------------
// offset conv, tap-split K-parallel, fp32 atomicAdd into zeroed offb.
// ---------------------------------------------------------------------------
__global__ void __launch_bounds__(256, 4) offset_kernel(
    const ushort_t* __restrict__ rt, const ushort_t* __restrict__ wofp,
    float* __restrict__ offb)
{
    const int tid  = threadIdx.x;
    const int wave = tid >> 6;
    const int lane = tid & 63;
    const int l15  = lane & 15;
    const int quad = lane >> 4;
    const int tap  = blockIdx.y;
    const int ky   = tap / 3 - 1, kx = tap % 3 - 1;
    const int pg   = blockIdx.x * 64 + wave * 16;
    const int n    = pg / HW;
    const int pi   = pg - n * HW;

    const int pl = pi + l15;
    const int h  = pl / W_, w = pl - h * W_;
    const int hy = h + ky, xr = w + kx;
    const bool valid = (hy >= 0) && (hy < H_) && (xr >= 0) && (xr < W_);
    const int hyc = min(max(hy, 0), H_ - 1);
    const int xc  = min(max(xr, 0), W_ - 1);
    const ushort_t* arow = rt + ((size_t)n * HW + hyc * W_ + xc) * 256 + quad * 8;

    float4v acc[2];
    acc[0] = (float4v)(0.f);
    acc[1] = (float4v)(0.f);

#pragma unroll
    for (int c0 = 0; c0 < 256; c0 += 32) {
        short8 af = valid ? *(const short8*)(arow + c0) : (short8)0;
#pragma unroll
        for (int nt = 0; nt < 2; ++nt) {
            short8 bf = *(const short8*)&wofp[(size_t)(tap * 32 + nt * 16 + l15) * 256 +
                                              c0 + quad * 8];
            acc[nt] = __builtin_amdgcn_mfma_f32_16x16x32_bf16(af, bf, acc[nt], 0, 0, 0);
        }
    }

#pragma unroll
    for (int nt = 0; nt < 2; ++nt) {
        int m = nt * 16 + l15;
        if (m < OFFC) {
#pragma unroll
            for (int rr = 0; rr < 4; ++rr) {
                int pi_row = pi + quad * 4 + rr;
                atomicAdd(&offb[((size_t)n * OFFC + m) * HW + pi_row], acc[nt][rr]);
            }
        }
    }
}

// ---------------------------------------------------------------------------
// deform conv: barrier-free global-fed, explicit depth-1 prefetch.
// Block 128 thr = 2 waves, SAME 16 p, o-halves 128 each (2x sampling dup).
// Grid (PTOT/16) = 784 blocks, 1568 waves. Corner loads for chunk c0+32 (or
// next tap's chunk 0) issued before blending chunk c0.
// ---------------------------------------------------------------------------
__global__ void __launch_bounds__(128, 2) deform_kernel(
    const ushort_t* __restrict__ rt, const float* __restrict__ offb,
    const float* __restrict__ b_off, const ushort_t* __restrict__ w2b,
    const float* __restrict__ b2, ushort_t* __restrict__ r2t)
{
    const int tid  = threadIdx.x;
    const int wave = tid >> 6;
    const int lane = tid & 63;
    const int l15  = lane & 15;
    const int quad = lane >> 4;
    const int pg    = blockIdx.x * 16;
    const int oBase = wave * 128;
    const int n     = pg / HW;
    const int pi    = pg - n * HW + l15;
    const int h = pi / W_, w = pi - h * W_;
    const ushort_t* rtn = rt + (size_t)n * HW * 256;
    const float* offn   = offb + (size_t)n * OFFC * HW;

    float4v acc[8];
#pragma unroll
    for (int j = 0; j < 8; ++j) acc[j] = (float4v)(0.f);

    float wcur[4];
    const ushort_t* ccur[4];
    float wnxt[4] = {0.f, 0.f, 0.f, 0.f};
    const ushort_t* cnxt[4] = {rtn, rtn, rtn, rtn};

    auto tapmeta = [&](int t, float* wd, const ushort_t** cd) {
        float dy = offn[(size_t)(2 * t) * HW + pi] + b_off[2 * t];
        float dx = offn[(size_t)(2 * t + 1) * HW + pi] + b_off[2 * t + 1];
        float ys = (float)(h + t / 3 - 1) + dy;
        float xs = (float)(w + t % 3 - 1) + dx;
        float y0f = floorf(ys), x0f = floorf(xs);
        int y0 = (int)y0f, x0 = (int)x0f;
        float wy1 = ys - y0f, wy0 = 1.f - wy1;
        float wx1 = xs - x0f, wx0 = 1.f - wx1;
#pragma unroll
        for (int u = 0; u < 2; ++u)
#pragma unroll
            for (int v = 0; v < 2; ++v) {
                int yy = y0 + u, xx = x0 + v;
                bool vld = (yy >= 0) && (yy < H_) && (xx >= 0) && (xx < W_);
                wd[u * 2 + v] = vld ? (u ? wy1 : wy0) * (v ? wx1 : wx0) : 0.f;
                int yc = min(max(yy, 0), H_ - 1);
                int xcc = min(max(xx, 0), W_ - 1);
                cd[u * 2 + v] = rtn + (size_t)(yc * W_ + xcc) * 256 + quad * 8;
            }
    };

    tapmeta(0, wcur, ccur);
    uint4v cw[4], cn[4];
#pragma unroll
    for (int j = 0; j < 4; ++j) cw[j] = *(const uint4v*)ccur[j];

    for (int kk = 0; kk < KK; ++kk) {
#pragma unroll
        for (int c0 = 0; c0 < 256; c0 += 32) {
            // issue next chunk's corner loads before consuming current
            if (c0 < 224) {
#pragma unroll
                for (int j = 0; j < 4; ++j)
                    cn[j] = *(const uint4v*)(ccur[j] + c0 + 32);
            } else if (kk < KK - 1) {
                tapmeta(kk + 1, wnxt, cnxt);
#pragma unroll
                for (int j = 0; j < 4; ++j)
                    cn[j] = *(const uint4v*)cnxt[j];
            }
            // bilinear blend -> bf16 A-fragment
            uint4v afu;
#pragma unroll
            for (int i = 0; i < 4; ++i) {
                float s0 = 0.f, s1 = 0.f;
#pragma unroll
                for (int j = 0; j < 4; ++j) {
                    unsigned int u = cw[j][i];
                    s0 = fmaf(wcur[j], __uint_as_float(u << 16), s0);
                    s1 = fmaf(wcur[j], __uint_as_float(u & 0xffff0000u), s1);
                }
                afu[i] = ((__float_as_uint(s0) + 0x8000u) >> 16) |
                         ((__float_as_uint(s1) + 0x8000u) & 0xffff0000u);
            }
            union { uint4v u; short8 s; } cvt;
            cvt.u = afu;
            short8 af = cvt.s;
#pragma unroll
            for (int nt = 0; nt < 8; ++nt) {
                short8 bf = *(const short8*)&w2b[(size_t)(oBase + nt * 16 + l15) * 2304 +
                                                 kk * 256 + c0 + quad * 8];
                acc[nt] = __builtin_amdgcn_mfma_f32_16x16x32_bf16(af, bf, acc[nt], 0, 0, 0);
            }
#pragma unroll
            for (int j = 0; j < 4; ++j) cw[j] = cn[j];
        }
#pragma unroll
        for (int j = 0; j < 4; ++j) { wcur[j] = wnxt[j]; ccur[j] = cnxt[j]; }
    }

#pragma unroll
    for (int rr = 0; rr < 4; ++rr) {
        int p_row = pg + quad * 4 + rr;
#pragma unroll
        for (int nt = 0; nt < 8; ++nt) {
            int o = oBase + nt * 16 + l15;
            float v = fmaxf(acc[nt][rr] + b2[o], 0.f);
            r2t[(size_t)p_row * 256 + o] = bf16_rne(v);
        }
    }
}

// ---------------------------------------------------------------------------
// conv3: out = relu(x + w3 . r2 + b3), NCHW fp32 out. Barrier-free.
// ---------------------------------------------------------------------------
__global__ void __launch_bounds__(256, 4) conv3_kernel(
    const ushort_t* __restrict__ w3p, const ushort_t* __restrict__ r2t,
    const float* __restrict__ b3, const float* __restrict__ x,
    float* __restrict__ out)
{
    const int tid  = threadIdx.x;
    const int wave = tid >> 6;
    const int lane = tid & 63;
    const int l15  = lane & 15;
    const int quad = lane >> 4;
    const int pBase = blockIdx.x * 64;
    const int n     = pBase / HW;
    const int p_in  = pBase % HW;
    const int mBase = blockIdx.y * 256 + wave * 64;

    float4v acc[4][4];
#pragma unroll
    for (int i = 0; i < 4; ++i)
#pragma unroll
        for (int j = 0; j < 4; ++j) acc[i][j] = (float4v)(0.f);

#pragma unroll
    for (int c0 = 0; c0 < 256; c0 += 32) {
        short8 bf[4];
#pragma unroll
        for (int nt = 0; nt < 4; ++nt)
            bf[nt] = *(const short8*)&r2t[(size_t)(pBase + nt * 16 + l15) * 256 +
                                          c0 + quad * 8];
#pragma unroll
        for (int mt = 0; mt < 4; ++mt) {
            short8 af = *(const short8*)&w3p[(size_t)(mBase + mt * 16 + l15) * 256 +
                                             c0 + quad * 8];
#pragma unroll
            for (int nt = 0; nt < 4; ++nt)
                acc[mt][nt] = __builtin_amdgcn_mfma_f32_16x16x32_bf16(
                    af, bf[nt], acc[mt][nt], 0, 0, 0);
        }
    }

#pragma unroll
    for (int mt = 0; mt < 4; ++mt)
#pragma unroll
        for (int rr = 0; rr < 4; ++rr) {
            int row = mBase + mt * 16 + quad * 4 + rr;
            float bv = b3[row];
#pragma unroll
            for (int nt = 0; nt < 4; ++nt) {
                int col = p_in + nt * 16 + l15;
                size_t idx = ((size_t)n * CIN + row) * HW + col;
                out[idx] = fmaxf(acc[mt][nt][rr] + bv + x[idx], 0.f);
            }
        }
}

// ---------------------------------------------------------------------------
// kernel_launch
// ---------------------------------------------------------------------------
extern "C" void kernel_launch(void* const* d_in, const int* in_sizes, int n_in,
                              void* d_out, int out_size, void* d_ws, size_t ws_size,
                              hipStream_t stream)
{
    const float* x     = (const float*)d_in[0];
    const float* w1    = (const float*)d_in[1];
    const float* b1    = (const float*)d_in[2];
    const float* w_off = (const float*)d_in[3];
    const float* b_off = (const float*)d_in[4];
    const float* w2    = (const float*)d_in[5];
    const float* b2    = (const float*)d_in[6];
    const float* w3    = (const float*)d_in[7];
    const float* b3    = (const float*)d_in[8];
    float* out = (float*)d_out;

    ushort_t* xt   = (ushort_t*)d_ws;                     // 12,845,056 ush
    ushort_t* rt   = xt + (size_t)PTOT * 1024;            //  3,211,264 ush
    ushort_t* r2t  = rt + (size_t)PTOT * 256;             //  3,211,264 ush
    float*    offb = (float*)(r2t + (size_t)PTOT * 256);  //    225,792 f
    ushort_t* w1p  = (ushort_t*)(offb + (size_t)N_ * OFFC * HW);
    ushort_t* w2b  = w1p + (size_t)256 * 1024;
    ushort_t* w3p  = w2b + (size_t)256 * 2304;
    ushort_t* wofp = w3p + (size_t)1024 * 256;

    // 1) pack weights (all single-plane bf16)
    {
        int total = 256 * 1024 + 256 * 2304 + 1024 * 256 + 9 * 32 * 256;
        pack_weights_kernel<<<(total + 255) / 256, 256, 0, stream>>>(
            w1, w2, w3, w_off, w1p, w2b, w3p, wofp);
    }
    // 2) xt = transpose(x) NHWC bf16
    {
        dim3 grid(PTOT / 64, CIN / 64);
        transpose_x_kernel<<<grid, 256, 0, stream>>>(x, xt);
    }
    // 3) rt = relu(xt . w1^T + b1)
    {
        dim3 grid(PTOT / 32, 2);
        conv1_kernel<<<grid, 256, 0, stream>>>(xt, w1p, b1, rt);
    }
    // 4) offb = conv3x3(rt, w_off)  (bias-free; tap-split atomic accumulate)
    hipMemsetAsync(offb, 0, (size_t)N_ * OFFC * HW * sizeof(float), stream);
    {
        dim3 grid(PTOT / 64, 9);
        offset_kernel<<<grid, 256, 0, stream>>>(rt, wofp, offb);
    }
    // 5) r2t = relu(deform(rt, offb + b_off) . w2 + b2)
    {
        dim3 grid(PTOT / 16);
        deform_kernel<<<grid, 128, 0, stream>>>(rt, offb, b_off, w2b, b2, r2t);
    }
    // 6) out = relu(x + w3 . r2 + b3)
    {
        dim3 grid(PTOT / 64, 4);
        conv3_kernel<<<grid, 256, 0, stream>>>(w3p, r2t, b3, x, out);
    }
}